// Round 21
// baseline (326.997 us; speedup 1.0000x reference)
//
#include <hip/hip_runtime.h>

using u16 = unsigned short;
using u32 = unsigned int;
typedef __attribute__((ext_vector_type(8))) _Float16 h8v;  // fp16x8 MFMA fragment (4 VGPRs)
typedef __attribute__((ext_vector_type(8))) u16 us8;       // raw 16B move
typedef __attribute__((ext_vector_type(2))) u32 u32x2;     // raw 8B move (ds_write_b64)
typedef __attribute__((ext_vector_type(4))) float f4v;     // fp32x4 accumulator

// ---------- helpers ----------
__device__ __forceinline__ u16 f2h(float f) {
  _Float16 h = (_Float16)f;                 // v_cvt_f16_f32, RNE
  return __builtin_bit_cast(unsigned short, h);
}
__device__ __forceinline__ _Float16 bits2h(u16 u) {
  return __builtin_bit_cast(_Float16, u);
}

__device__ __forceinline__ f4v mfma16(h8v a, h8v b, f4v c) {
  return __builtin_amdgcn_mfma_f32_16x16x32_f16(a, b, c, 0, 0, 0);
}

__device__ __forceinline__ void gll16(const void* g, void* l) {
  __builtin_amdgcn_global_load_lds(
      (const __attribute__((address_space(1))) void*)g,
      (__attribute__((address_space(3))) void*)l, 16, 0, 0);
}

// Problem constants
// B=16, C=512, W=64, H=64, OUT=512, NH=8, HD=64, hd2=32, seq K=64
// qkv_ws layout: [s=(b*64+h)][wseq][o 0..1024) fp16 ; attn_ws: [s][wseq][C) fp16

// ---------- setup: fp16 weight copies + gathered/transposed emb tables ----------
__global__ __launch_bounds__(256) void k0_setup(
    const float* __restrict__ w1, const float* __restrict__ wout,
    const float* __restrict__ rel, u16* __restrict__ W1b, u16* __restrict__ Woutb,
    u16* __restrict__ EqT, u16* __restrict__ EkT, u16* __restrict__ Evp)
{
  int idx = blockIdx.x * 256 + threadIdx.x;
  if (idx < 524288) {                       // W1b [1024][512]
    W1b[idx] = f2h(w1[idx]);
  } else if (idx < 786432) {                // Woutb [512][512]
    int k = idx - 524288; Woutb[k] = f2h(wout[k]);
  } else if (idx < 790528) {                // EqT [t 128][c 32] = rel[c][t]
    int k = idx - 786432; int t = k >> 5, c = k & 31;
    EqT[k] = (t < 127) ? f2h(rel[c * 127 + t]) : (u16)0;
  } else if (idx < 794624) {                // EkT [t 128][c 32] = rel[32+c][t]
    int k = idx - 790528; int t = k >> 5, c = k & 31;
    EkT[k] = (t < 127) ? f2h(rel[(32 + c) * 127 + t]) : (u16)0;
  } else if (idx < 802816) {                // Evp [c 64][t 128] = rel[64+c][t]
    int k = idx - 794624; int c = k >> 7, t = k & 127;
    Evp[k] = (t < 127) ? f2h(rel[(64 + c) * 127 + t]) : (u16)0;
  }
}

// ---------- K1 (best-measured R10 config): qkv = x @ W1^T + b ----------
// Fused transpose (coalesced along h) -> swizzled XL; W via LDS dbuf; 80KB, 2 blk/CU.
__global__ __launch_bounds__(256, 2) void k1_qkv(
    const float* __restrict__ x, const u16* __restrict__ W1b,
    const float* __restrict__ bias, u16* __restrict__ qkv)
{
  __shared__ u16 POOL[40960];          // 80KB: XL 64x512 (64KB) + W dbuf 2x4096 u16 (16KB)
  u16* XL = POOL;                      // [h 64][chunk 64, ^ (h&7)]
  u16* WD = POOL + 32768;              // [buf 2][o 128][c4 4, ^ ((o>>1)&3)] ; epi: Tr 16KB
  const int bid = blockIdx.x;          // = b*64 + w
  const int b = bid >> 6, w = bid & 63;
  const int tid = threadIdx.x;
  const int l = tid & 63, wv = tid >> 6;
  const int lr = l & 15, lg = l >> 4;
  const int osub = (wv & 1) * 64;      // 4 waves: 2(o) x 2(r)
  const int rsub = (wv >> 1) * 32;

  // ---- W stage: [128 o][32 ch] per (ot,kk), 2 gll16/thread, src pre-swizzled ----
  auto stageB = [&](int ot, int kk, int buf) {
#pragma unroll
    for (int q = 0; q < 2; q++) {
      int slot = q * 256 + tid;        // 0..511 ; LDS dest linear = slot*16B
      int o = slot >> 2, c4 = slot & 3;
      gll16(W1b + (size_t)(ot * 128 + o) * 512 + kk * 32 +
                ((c4 ^ ((o >> 1) & 3)) << 3),
            WD + buf * 4096 + slot * 8);
    }
  };

  stageB(0, 0, 0);                     // W latency hides under the transpose below

  // ---- fused x transpose-stage: 16 us8/thread, 8 coalesced dword loads each ----
  {
    const int r = tid & 63;            // h row (wave spans 64 consecutive h)
    const int cb = tid >> 6;           // chunk low bits
    const float* xb = x + ((size_t)b * 512 * 64 + w) * 64 + r;
#pragma unroll
    for (int q = 0; q < 16; q++) {
      int cc = (q << 2) | cb;          // chunk 0..63 (c = cc*8..+7)
      float v[8];
#pragma unroll
      for (int e = 0; e < 8; e++)
        v[e] = xb[(size_t)(cc * 8 + e) * 4096];
      us8 o;
#pragma unroll
      for (int e = 0; e < 8; e++) o[e] = f2h(v[e]);
      *(us8*)&XL[r * 512 + ((cc ^ (r & 7)) << 3)] = o;
    }
  }
  __syncthreads();                     // XL + first W tile resident

  for (int ot = 0; ot < 8; ot++) {
    const int o0 = ot * 128;
    f4v acc[4][2];
#pragma unroll
    for (int mt = 0; mt < 4; mt++)
#pragma unroll
      for (int nt = 0; nt < 2; nt++) acc[mt][nt] = (f4v){0.f, 0.f, 0.f, 0.f};

#pragma unroll
    for (int kk = 0; kk < 16; kk++) {
      int cur = kk & 1;
      if (kk < 15) stageB(ot, kk + 1, cur ^ 1);   // async prefetch next W tile
      h8v wf[4], xf[2];
#pragma unroll
      for (int mt = 0; mt < 4; mt++) {
        int o = osub + mt * 16 + lr;
        wf[mt] = *(const h8v*)&WD[cur * 4096 + o * 32 +
                                  ((lg ^ ((o >> 1) & 3)) << 3)];
      }
#pragma unroll
      for (int nt = 0; nt < 2; nt++) {
        int r = rsub + nt * 16 + lr;
        int cc = kk * 4 + lg;
        xf[nt] = *(const h8v*)&XL[r * 512 + ((cc ^ (r & 7)) << 3)];
      }
#pragma unroll
      for (int mt = 0; mt < 4; mt++)
#pragma unroll
        for (int nt = 0; nt < 2; nt++)
          acc[mt][nt] = mfma16(wf[mt], xf[nt], acc[mt][nt]);
      __syncthreads();                 // drains vmcnt -> next tile visible
    }

    // ---- epilogue: Tr overlays the W-dbuf region (16KB = [r 64][o-chunk 16 swz]) ----
    u16* Tr = WD;
    float4 bias4[4];
#pragma unroll
    for (int mt = 0; mt < 4; mt++)
      bias4[mt] = *(const float4*)&bias[o0 + osub + mt * 16 + lg * 4];
#pragma unroll
    for (int mt = 0; mt < 4; mt++)
#pragma unroll
      for (int nt = 0; nt < 2; nt++) {
        int r = rsub + nt * 16 + lr;
#pragma unroll
        for (int ep = 0; ep < 2; ep++) {
          int o_ = osub + mt * 16 + lg * 4 + 2 * ep;
          float v0 = acc[mt][nt][2 * ep + 0] + ((const float*)&bias4[mt])[2 * ep + 0];
          float v1 = acc[mt][nt][2 * ep + 1] + ((const float*)&bias4[mt])[2 * ep + 1];
          unsigned pk = (unsigned)f2h(v0) | ((unsigned)f2h(v1) << 16);
          int cc = o_ >> 3;
          int dst = (cc & 8) | ((cc & 7) ^ (r & 7));
          *(unsigned*)&Tr[r * 128 + dst * 8 + (o_ & 7)] = pk;
        }
      }
    __syncthreads();
#pragma unroll
    for (int p = 0; p < 4; p++) {      // 256B-contiguous row stores
      int u = p * 256 + tid;           // 0..1023 = 64 rows x 16 chunks
      int r = u >> 4, cc = u & 15;
      int dst = (cc & 8) | ((cc & 7) ^ (r & 7));
      us8 v = *(const us8*)&Tr[r * 128 + dst * 8];
      size_t S = (size_t)(b * 64 + r) * 64 + w;
      *(us8*)&qkv[S * 1024 + o0 + cc * 8] = v;
    }
    __syncthreads();                   // Tr reads done -> region reusable as W dbuf
    if (ot < 7) { stageB(ot + 1, 0, 0); __syncthreads(); }
  }
}

// ---------- K2: attention per (slice s, head g). Swapped-QK: lane owns ONE i-row ----------
// g-major decode: s = bid & 1023, g = bid >> 10 (single dispatch).
__global__ __launch_bounds__(256) void k2_attn(
    const u16* __restrict__ qkv, const u16* __restrict__ EqT,
    const u16* __restrict__ EkT, const u16* __restrict__ Evp,
    u16* __restrict__ attn)
{
  const int bid = blockIdx.x;
  const int s = bid & 1023, g = bid >> 10;
  const int tid = threadIdx.x;
  const int l = tid & 63, wv = tid >> 6;
  const int lr = l & 15, lg = l >> 4;
  const int i0 = wv * 16;
  const u16* base = qkv + (size_t)s * 65536;

  __shared__ __align__(16) u16 POOL[16896];  // 33792 B
  u16* QEi = POOL;                   // [i 64][t 132]  QE[i][t], t in [0,127)
  u16* KEj = POOL + 8448;            // [j 64][t' 132] KE[t'][j] stored row-j
  u16* Pl  = POOL;                   // overlay: [i 64][j 64] chunk^(i&7)  (8192 B)
  u16* VTl = POOL + 4096;            // overlay: [c 64][j 64] chunk^(c&7)  (8192 B)
  u16* Psh = POOL + 8192;            // overlay: [i 64][d 128] chunk-swz  (16384 B)

  // issue V loads early; held in regs through the MFMA phase
  us8 vreg0, vreg1;
  {
    int u0 = tid,        j0_ = u0 >> 3, cb0 = u0 & 7;
    int u1 = tid + 256,  j1_ = u1 >> 3, cb1 = u1 & 7;
    vreg0 = *(const us8*)(base + j0_ * 1024 + 512 + g * 64 + cb0 * 8);
    vreg1 = *(const us8*)(base + j1_ * 1024 + 512 + g * 64 + cb1 * 8);
  }

  // Q / K fragments (both natural [pos][chan] -> k-contiguous)
  h8v qf = *(const h8v*)(base + (i0 + lr) * 1024 + g * 32 + lg * 8);
  h8v kf[4];
#pragma unroll
  for (int jt = 0; jt < 4; jt++)
    kf[jt] = *(const h8v*)(base + (jt * 16 + lr) * 1024 + 256 + g * 32 + lg * 8);

  const f4v z4 = {0.f, 0.f, 0.f, 0.f};

  // QE^T = mfma(Eq-rows, Q-rows): D[m=t][n=i] -> lane holds t=tt*16+4lg+e, i=i0+lr.
#pragma unroll
  for (int tt = 0; tt < 8; tt++) {
    h8v eb = *(const h8v*)(EqT + (tt * 16 + lr) * 32 + lg * 8);
    f4v d = mfma16(eb, qf, z4);
    int tb = tt * 16 + 4 * lg;
    u32x2 pk;
    pk[0] = (u32)f2h(d[0]) | ((u32)f2h(d[1]) << 16);
    pk[1] = (u32)f2h(d[2]) | ((u32)f2h(d[3]) << 16);
    *(u32x2*)&QEi[(i0 + lr) * 132 + tb] = pk;
  }
  // KE = mfma(Ek-rows, K-rows): D[m=t'][n=j] -> lane t'=tt*16+4lg+e, j=jt*16+lr.
#pragma unroll
  for (int q = 0; q < 2; q++) {
    int tt = wv * 2 + q;
    h8v ea = *(const h8v*)(EkT + (tt * 16 + lr) * 32 + lg * 8);
#pragma unroll
    for (int jt = 0; jt < 4; jt++) {
      f4v d = mfma16(ea, kf[jt], z4);
      int tb = tt * 16 + 4 * lg;
      u32x2 pk;
      pk[0] = (u32)f2h(d[0]) | ((u32)f2h(d[1]) << 16);
      pk[1] = (u32)f2h(d[2]) | ((u32)f2h(d[3]) << 16);
      *(u32x2*)&KEj[(jt * 16 + lr) * 132 + tb] = pk;
    }
  }
  // qk SWAPPED: sc[jt] = mfma(K-rows, Q-rows): D[m=j][n=i] -> lane holds
  // S[i=i0+lr][j=jt*16+4lg+e] — one attention row per lane.
  f4v sc[4];
#pragma unroll
  for (int jt = 0; jt < 4; jt++) sc[jt] = mfma16(kf[jt], qf, z4);

  __syncthreads();   // QEi/KEj visible

  // row-local band gather + softmax (lane owns row i = i0+lr entirely)
  const int i = i0 + lr;
  float pv[4][4];    // [jt][e]
  {
    int qbase = i * 133 + 63 - 4 * lg;          // QEi: off = i*132 + (i+63-j)
    int kbase = 8448 + 4 * lg * 133 + 63 - i;   // KEj: off = j*132 + (63+j-i)
#pragma unroll
    for (int jt = 0; jt < 4; jt++)
#pragma unroll
      for (int e = 0; e < 4; e++) {
        float qr = (float)bits2h(POOL[qbase - 16 * jt - e]);
        float kr = (float)bits2h(POOL[kbase + 2128 * jt + 133 * e]);
        pv[jt][e] = sc[jt][e] + qr + kr;
      }
  }
  float inv;
  {
    float m = pv[0][0];
#pragma unroll
    for (int jt = 0; jt < 4; jt++)
#pragma unroll
      for (int e = 0; e < 4; e++) m = fmaxf(m, pv[jt][e]);
    m = fmaxf(m, __shfl_xor(m, 16));
    m = fmaxf(m, __shfl_xor(m, 32));
    float t0 = 0.f;
#pragma unroll
    for (int jt = 0; jt < 4; jt++)
#pragma unroll
      for (int e = 0; e < 4; e++) {
        pv[jt][e] = exp2f((pv[jt][e] - m) * 1.4426950408889634f);
        t0 += pv[jt][e];
      }
    t0 += __shfl_xor(t0, 16);
    t0 += __shfl_xor(t0, 32);
    inv = 1.f / t0;
  }
#pragma unroll
  for (int jt = 0; jt < 4; jt++)
#pragma unroll
    for (int e = 0; e < 4; e++) pv[jt][e] *= inv;   // pre-normalize

  __syncthreads();   // all gathers done -> safe to overlay Pl/VTl/Psh

  // write P: Pl[i][j] (b64: j-run of 4 inside one 8-chunk) + Psh[i][d] (scalar)
#pragma unroll
  for (int jt = 0; jt < 4; jt++) {
    int j0 = jt * 16 + 4 * lg;
    int jc = j0 >> 3;
    u32x2 pk;
    pk[0] = (u32)f2h(pv[jt][0]) | ((u32)f2h(pv[jt][1]) << 16);
    pk[1] = (u32)f2h(pv[jt][2]) | ((u32)f2h(pv[jt][3]) << 16);
    *(u32x2*)&Pl[i * 64 + ((jc ^ (i & 7)) << 3) + (j0 & 7)] = pk;
#pragma unroll
    for (int e = 0; e < 4; e++) {
      int d = i + 63 - (j0 + e);
      int cd = d >> 3;
      Psh[i * 128 + (((cd & 8) | ((cd & 7) ^ (i & 7))) << 3) + (d & 7)] =
          f2h(pv[jt][e]);
    }
  }
  {
    // zero out-of-band Psh cells: row zi, 64 invalid cols split [0,zi) u [zi+64,128)
    int zi = tid >> 2;
#pragma unroll
    for (int kk = 0; kk < 16; kk++) {
      int k = (tid & 3) * 16 + kk;
      int col = (k < zi) ? k : (k + 64);
      int cd = col >> 3;
      Psh[zi * 128 + (((cd & 8) | ((cd & 7) ^ (zi & 7))) << 3) + (col & 7)] = 0;
    }
    int u0 = tid, j0_ = u0 >> 3, cb0 = u0 & 7;
#pragma unroll
    for (int e = 0; e < 8; e++) {
      int c = cb0 * 8 + e;
      VTl[c * 64 + (((j0_ >> 3) ^ (c & 7)) << 3) + (j0_ & 7)] = (u16)vreg0[e];
    }
    int u1 = tid + 256, j1_ = u1 >> 3, cb1 = u1 & 7;
#pragma unroll
    for (int e = 0; e < 8; e++) {
      int c = cb1 * 8 + e;
      VTl[c * 64 + (((j1_ >> 3) ^ (c & 7)) << 3) + (j1_ & 7)] = (u16)vreg1[e];
    }
  }
  __syncthreads();   // P / VT / Psh visible

  // PV + SVE accumulate into [i 16][c 64] (P pre-normalized)
  f4v acc[4] = {z4, z4, z4, z4};
  {
#pragma unroll
    for (int kc = 0; kc < 2; kc++) {
      h8v pa = *(const h8v*)&Pl[i * 64 + (((kc * 4 + lg) ^ (i & 7)) << 3)];
#pragma unroll
      for (int ct = 0; ct < 4; ct++) {
        int cA = ct * 16 + lr;
        h8v vb = *(const h8v*)&VTl[cA * 64 + (((kc * 4 + lg) ^ (cA & 7)) << 3)];
        acc[ct] = mfma16(pa, vb, acc[ct]);
      }
    }
    // SVE: Pshift[i][d] (A) x Evp[c][d] (B), K=128
#pragma unroll
    for (int tc = 0; tc < 4; tc++) {
      int cd = tc * 4 + lg;
      int cds = (cd & 8) | ((cd & 7) ^ (i & 7));
      h8v pa = *(const h8v*)&Psh[i * 128 + cds * 8];
#pragma unroll
      for (int ct = 0; ct < 4; ct++) {
        h8v eb = *(const h8v*)(Evp + (ct * 16 + lr) * 128 + tc * 32 + lg * 8);
        acc[ct] = mfma16(pa, eb, acc[ct]);
      }
    }
  }
  // store attn rows [s*64+i][g*64+c] (already normalized)
#pragma unroll
  for (int ct = 0; ct < 4; ct++)
#pragma unroll
    for (int r = 0; r < 4; r++) {
      int io = i0 + lg * 4 + r;
      attn[(size_t)(s * 64 + io) * 512 + g * 64 + ct * 16 + lr] = f2h(acc[ct][r]);
    }
}

// ---------- K3: out = attn @ Wout^T + b. W via async LDS dbuf (R16 form) ----------
__global__ __launch_bounds__(512, 4) void k3_oproj(
    const u16* __restrict__ attn, const u16* __restrict__ Woutb,
    const float* __restrict__ ob, float* __restrict__ out)
{
  __shared__ u16 POOL3[40960];     // 80KB: WD 2x16384 u16 (64KB) + Bl 2x4096 u16 (16KB)
  u16* WD = POOL3;                 // [buf][o 512][c4 4, ^ ((o>>1)&3)]
  u16* Bl = POOL3 + 32768;         // [buf][h 64][chunk 8, ^ (h&7)] (64 c per pair)
  const int bid = blockIdx.x;
  const int b = bid >> 6, w = bid & 63;
  const int tid = threadIdx.x;
  const int l = tid & 63, wv = tid >> 6;   // 8 waves, wave owns o [wv*64, +64)
  const int lr = l & 15, lg = l >> 4;
  const int osub = wv * 64;

  auto stageW = [&](int kk, int buf) {     // [512 o][32 c], 4 gll16/thread
#pragma unroll
    for (int q = 0; q < 4; q++) {
      int slot = q * 512 + tid;
      int o = slot >> 2, c4 = slot & 3;
      gll16(Woutb + (size_t)o * 512 + kk * 32 + ((c4 ^ ((o >> 1) & 3)) << 3),
            WD + buf * 16384 + slot * 8);
    }
  };
  auto stageA = [&](int pr, int buf) {     // attn pair pr: 64 c, 1 gll16/thread
    int h_l = tid >> 3, p = tid & 7;
    gll16(attn + ((size_t)b * 4096 + (size_t)h_l * 64 + w) * 512 + pr * 64 +
              ((p ^ (h_l & 7)) << 3),
          Bl + buf * 4096 + tid * 8);
  };

  stageW(0, 0);
  stageA(0, 0);
  __syncthreads();

  f4v acc[4][4];
#pragma unroll
  for (int mt = 0; mt < 4; mt++)
#pragma unroll
    for (int jt = 0; jt < 4; jt++) acc[mt][jt] = (f4v){0.f, 0.f, 0.f, 0.f};

  for (int kk = 0; kk < 16; kk++) {        // BK=32; c = kk*32 (same order as before)
    int curW = kk & 1;
    int pr = kk >> 1, curA = pr & 1;
    if (kk < 15) stageW(kk + 1, curW ^ 1);
    if ((kk & 1) == 0 && pr < 7) stageA(pr + 1, curA ^ 1);
    h8v af[4], bf[4];
#pragma unroll
    for (int mt = 0; mt < 4; mt++) {
      int o = osub + mt * 16 + lr;
      af[mt] = *(const h8v*)&WD[curW * 16384 + o * 32 +
                                ((lg ^ ((o >> 1) & 3)) << 3)];
    }
#pragma unroll
    for (int jt = 0; jt < 4; jt++) {
      int h = jt * 16 + lr;
      bf[jt] = *(const h8v*)&Bl[curA * 4096 + h * 64 +
                                ((((kk & 1) * 4 + lg) ^ (h & 7)) << 3)];
    }
#pragma unroll
    for (int mt = 0; mt < 4; mt++)
#pragma unroll
      for (int jt = 0; jt < 4; jt++)
        acc[mt][jt] = mfma16(af[mt], bf[jt], acc[mt][jt]);
    __syncthreads();                       // drains vmcnt -> next tiles visible
  }

#pragma unroll
  for (int mt = 0; mt < 4; mt++)
#pragma unroll
    for (int jt = 0; jt < 4; jt++)
#pragma unroll
      for (int e = 0; e < 4; e++) {
        int o = osub + mt * 16 + lg * 4 + e;
        int h = jt * 16 + lr;
        out[(((size_t)b * 512 + o) * 64 + w) * 64 + h] = acc[mt][jt][e] + ob[o];
      }
}

// ---------- launch ----------
extern "C" void kernel_launch(void* const* d_in, const int* in_sizes, int n_in,
                              void* d_out, int out_size, void* d_ws, size_t ws_size,
                              hipStream_t stream)
{
  (void)in_sizes; (void)n_in; (void)out_size; (void)ws_size;
  const float* x    = (const float*)d_in[0];
  const float* w1   = (const float*)d_in[1];
  const float* b1   = (const float*)d_in[2];
  const float* wout = (const float*)d_in[3];
  const float* bo   = (const float*)d_in[4];
  const float* rel  = (const float*)d_in[5];
  float* out = (float*)d_out;

  char* ws = (char*)d_ws;                       // needs ~193.6 MiB
  u16* qkv_ws  = (u16*)ws;                      // 134,217,728 B
  u16* attn_ws = (u16*)(ws + 134217728);        //  67,108,864 B
  u16* W1b     = (u16*)(ws + 201326592);        //   1,048,576 B
  u16* Woutb   = (u16*)(ws + 202375168);        //     524,288 B
  u16* EqT     = (u16*)(ws + 202899456);        //       8,192 B
  u16* EkT     = (u16*)(ws + 202907648);        //       8,192 B
  u16* Evp     = (u16*)(ws + 202915840);        //      16,384 B

  k0_setup<<<dim3(3136), dim3(256), 0, stream>>>(w1, wout, rel, W1b, Woutb, EqT, EkT, Evp);
  k1_qkv  <<<dim3(1024), dim3(256), 0, stream>>>(x, W1b, b1, qkv_ws);
  k2_attn <<<dim3(8192), dim3(256), 0, stream>>>(qkv_ws, EqT, EkT, Evp, attn_ws);
  k3_oproj<<<dim3(1024), dim3(512), 0, stream>>>(attn_ws, Woutb, bo, out);
}

// Round 22
// 326.440 us; speedup vs baseline: 1.0017x; 1.0017x over previous
//
#include <hip/hip_runtime.h>

using u16 = unsigned short;
using u32 = unsigned int;
typedef __attribute__((ext_vector_type(8))) _Float16 h8v;  // fp16x8 MFMA fragment (4 VGPRs)
typedef __attribute__((ext_vector_type(8))) u16 us8;       // raw 16B move
typedef __attribute__((ext_vector_type(2))) u32 u32x2;     // raw 8B move (ds_write_b64)
typedef __attribute__((ext_vector_type(4))) float f4v;     // fp32x4 accumulator

// ---------- helpers ----------
__device__ __forceinline__ u16 f2h(float f) {
  _Float16 h = (_Float16)f;                 // v_cvt_f16_f32, RNE
  return __builtin_bit_cast(unsigned short, h);
}
__device__ __forceinline__ _Float16 bits2h(u16 u) {
  return __builtin_bit_cast(_Float16, u);
}

__device__ __forceinline__ f4v mfma16(h8v a, h8v b, f4v c) {
  return __builtin_amdgcn_mfma_f32_16x16x32_f16(a, b, c, 0, 0, 0);
}

__device__ __forceinline__ void gll16(const void* g, void* l) {
  __builtin_amdgcn_global_load_lds(
      (const __attribute__((address_space(1))) void*)g,
      (__attribute__((address_space(3))) void*)l, 16, 0, 0);
}

// Problem constants
// B=16, C=512, W=64, H=64, OUT=512, NH=8, HD=64, hd2=32, seq K=64
// qkv_ws layout: [s=(b*64+h)][wseq][o 0..1024) fp16 ; attn_ws: [s][wseq][C) fp16

// ---------- setup: fp16 weight copies + gathered/transposed emb tables ----------
__global__ __launch_bounds__(256) void k0_setup(
    const float* __restrict__ w1, const float* __restrict__ wout,
    const float* __restrict__ rel, u16* __restrict__ W1b, u16* __restrict__ Woutb,
    u16* __restrict__ EqT, u16* __restrict__ EkT, u16* __restrict__ Evp)
{
  int idx = blockIdx.x * 256 + threadIdx.x;
  if (idx < 524288) {                       // W1b [1024][512]
    W1b[idx] = f2h(w1[idx]);
  } else if (idx < 786432) {                // Woutb [512][512]
    int k = idx - 524288; Woutb[k] = f2h(wout[k]);
  } else if (idx < 790528) {                // EqT [t 128][c 32] = rel[c][t]
    int k = idx - 786432; int t = k >> 5, c = k & 31;
    EqT[k] = (t < 127) ? f2h(rel[c * 127 + t]) : (u16)0;
  } else if (idx < 794624) {                // EkT [t 128][c 32] = rel[32+c][t]
    int k = idx - 790528; int t = k >> 5, c = k & 31;
    EkT[k] = (t < 127) ? f2h(rel[(32 + c) * 127 + t]) : (u16)0;
  } else if (idx < 802816) {                // Evp [c 64][t 128] = rel[64+c][t]
    int k = idx - 794624; int c = k >> 7, t = k & 127;
    Evp[k] = (t < 127) ? f2h(rel[(64 + c) * 127 + t]) : (u16)0;
  }
}

// ---------- K1 (best-measured R10 config): qkv = x @ W1^T + b ----------
// Fused transpose (coalesced along h) -> swizzled XL; W via LDS dbuf; 80KB, 2 blk/CU.
__global__ __launch_bounds__(256, 2) void k1_qkv(
    const float* __restrict__ x, const u16* __restrict__ W1b,
    const float* __restrict__ bias, u16* __restrict__ qkv)
{
  __shared__ u16 POOL[40960];          // 80KB: XL 64x512 (64KB) + W dbuf 2x4096 u16 (16KB)
  u16* XL = POOL;                      // [h 64][chunk 64, ^ (h&7)]
  u16* WD = POOL + 32768;              // [buf 2][o 128][c4 4, ^ ((o>>1)&3)] ; epi: Tr 16KB
  const int bid = blockIdx.x;          // = b*64 + w
  const int b = bid >> 6, w = bid & 63;
  const int tid = threadIdx.x;
  const int l = tid & 63, wv = tid >> 6;
  const int lr = l & 15, lg = l >> 4;
  const int osub = (wv & 1) * 64;      // 4 waves: 2(o) x 2(r)
  const int rsub = (wv >> 1) * 32;

  // ---- W stage: [128 o][32 ch] per (ot,kk), 2 gll16/thread, src pre-swizzled ----
  auto stageB = [&](int ot, int kk, int buf) {
#pragma unroll
    for (int q = 0; q < 2; q++) {
      int slot = q * 256 + tid;        // 0..511 ; LDS dest linear = slot*16B
      int o = slot >> 2, c4 = slot & 3;
      gll16(W1b + (size_t)(ot * 128 + o) * 512 + kk * 32 +
                ((c4 ^ ((o >> 1) & 3)) << 3),
            WD + buf * 4096 + slot * 8);
    }
  };

  stageB(0, 0, 0);                     // W latency hides under the transpose below

  // ---- fused x transpose-stage: 16 us8/thread, 8 coalesced dword loads each ----
  {
    const int r = tid & 63;            // h row (wave spans 64 consecutive h)
    const int cb = tid >> 6;           // chunk low bits
    const float* xb = x + ((size_t)b * 512 * 64 + w) * 64 + r;
#pragma unroll
    for (int q = 0; q < 16; q++) {
      int cc = (q << 2) | cb;          // chunk 0..63 (c = cc*8..+7)
      float v[8];
#pragma unroll
      for (int e = 0; e < 8; e++)
        v[e] = xb[(size_t)(cc * 8 + e) * 4096];
      us8 o;
#pragma unroll
      for (int e = 0; e < 8; e++) o[e] = f2h(v[e]);
      *(us8*)&XL[r * 512 + ((cc ^ (r & 7)) << 3)] = o;
    }
  }
  __syncthreads();                     // XL + first W tile resident

  for (int ot = 0; ot < 8; ot++) {
    const int o0 = ot * 128;
    f4v acc[4][2];
#pragma unroll
    for (int mt = 0; mt < 4; mt++)
#pragma unroll
      for (int nt = 0; nt < 2; nt++) acc[mt][nt] = (f4v){0.f, 0.f, 0.f, 0.f};

#pragma unroll
    for (int kk = 0; kk < 16; kk++) {
      int cur = kk & 1;
      if (kk < 15) stageB(ot, kk + 1, cur ^ 1);   // async prefetch next W tile
      h8v wf[4], xf[2];
#pragma unroll
      for (int mt = 0; mt < 4; mt++) {
        int o = osub + mt * 16 + lr;
        wf[mt] = *(const h8v*)&WD[cur * 4096 + o * 32 +
                                  ((lg ^ ((o >> 1) & 3)) << 3)];
      }
#pragma unroll
      for (int nt = 0; nt < 2; nt++) {
        int r = rsub + nt * 16 + lr;
        int cc = kk * 4 + lg;
        xf[nt] = *(const h8v*)&XL[r * 512 + ((cc ^ (r & 7)) << 3)];
      }
#pragma unroll
      for (int mt = 0; mt < 4; mt++)
#pragma unroll
        for (int nt = 0; nt < 2; nt++)
          acc[mt][nt] = mfma16(wf[mt], xf[nt], acc[mt][nt]);
      __syncthreads();                 // drains vmcnt -> next tile visible
    }

    // ---- epilogue: Tr overlays the W-dbuf region (16KB = [r 64][o-chunk 16 swz]) ----
    u16* Tr = WD;
    float4 bias4[4];
#pragma unroll
    for (int mt = 0; mt < 4; mt++)
      bias4[mt] = *(const float4*)&bias[o0 + osub + mt * 16 + lg * 4];
#pragma unroll
    for (int mt = 0; mt < 4; mt++)
#pragma unroll
      for (int nt = 0; nt < 2; nt++) {
        int r = rsub + nt * 16 + lr;
#pragma unroll
        for (int ep = 0; ep < 2; ep++) {
          int o_ = osub + mt * 16 + lg * 4 + 2 * ep;
          float v0 = acc[mt][nt][2 * ep + 0] + ((const float*)&bias4[mt])[2 * ep + 0];
          float v1 = acc[mt][nt][2 * ep + 1] + ((const float*)&bias4[mt])[2 * ep + 1];
          unsigned pk = (unsigned)f2h(v0) | ((unsigned)f2h(v1) << 16);
          int cc = o_ >> 3;
          int dst = (cc & 8) | ((cc & 7) ^ (r & 7));
          *(unsigned*)&Tr[r * 128 + dst * 8 + (o_ & 7)] = pk;
        }
      }
    __syncthreads();
#pragma unroll
    for (int p = 0; p < 4; p++) {      // 256B-contiguous row stores
      int u = p * 256 + tid;           // 0..1023 = 64 rows x 16 chunks
      int r = u >> 4, cc = u & 15;
      int dst = (cc & 8) | ((cc & 7) ^ (r & 7));
      us8 v = *(const us8*)&Tr[r * 128 + dst * 8];
      size_t S = (size_t)(b * 64 + r) * 64 + w;
      *(us8*)&qkv[S * 1024 + o0 + cc * 8] = v;
    }
    __syncthreads();                   // Tr reads done -> region reusable as W dbuf
    if (ot < 7) { stageB(ot + 1, 0, 0); __syncthreads(); }
  }
}

// ---------- K2: attention per (slice s, head g). Swapped-QK: lane owns ONE i-row ----------
// g-major decode: s = bid & 1023, g = bid >> 10 (single dispatch).
__global__ __launch_bounds__(256) void k2_attn(
    const u16* __restrict__ qkv, const u16* __restrict__ EqT,
    const u16* __restrict__ EkT, const u16* __restrict__ Evp,
    u16* __restrict__ attn)
{
  const int bid = blockIdx.x;
  const int s = bid & 1023, g = bid >> 10;
  const int tid = threadIdx.x;
  const int l = tid & 63, wv = tid >> 6;
  const int lr = l & 15, lg = l >> 4;
  const int i0 = wv * 16;
  const u16* base = qkv + (size_t)s * 65536;

  __shared__ __align__(16) u16 POOL[16896];  // 33792 B
  u16* QEi = POOL;                   // [i 64][t 132]  QE[i][t], t in [0,127)
  u16* KEj = POOL + 8448;            // [j 64][t' 132] KE[t'][j] stored row-j
  u16* Pl  = POOL;                   // overlay: [i 64][j 64] chunk^(i&7)  (8192 B)
  u16* VTl = POOL + 4096;            // overlay: [c 64][j 64] chunk^(c&7)  (8192 B)
  u16* Psh = POOL + 8192;            // overlay: [i 64][d 128] chunk-swz  (16384 B)

  // issue V loads early; held in regs through the MFMA phase
  us8 vreg0, vreg1;
  {
    int u0 = tid,        j0_ = u0 >> 3, cb0 = u0 & 7;
    int u1 = tid + 256,  j1_ = u1 >> 3, cb1 = u1 & 7;
    vreg0 = *(const us8*)(base + j0_ * 1024 + 512 + g * 64 + cb0 * 8);
    vreg1 = *(const us8*)(base + j1_ * 1024 + 512 + g * 64 + cb1 * 8);
  }

  // Q / K fragments (both natural [pos][chan] -> k-contiguous)
  h8v qf = *(const h8v*)(base + (i0 + lr) * 1024 + g * 32 + lg * 8);
  h8v kf[4];
#pragma unroll
  for (int jt = 0; jt < 4; jt++)
    kf[jt] = *(const h8v*)(base + (jt * 16 + lr) * 1024 + 256 + g * 32 + lg * 8);

  const f4v z4 = {0.f, 0.f, 0.f, 0.f};

  // QE^T = mfma(Eq-rows, Q-rows): D[m=t][n=i] -> lane holds t=tt*16+4lg+e, i=i0+lr.
#pragma unroll
  for (int tt = 0; tt < 8; tt++) {
    h8v eb = *(const h8v*)(EqT + (tt * 16 + lr) * 32 + lg * 8);
    f4v d = mfma16(eb, qf, z4);
    int tb = tt * 16 + 4 * lg;
    u32x2 pk;
    pk[0] = (u32)f2h(d[0]) | ((u32)f2h(d[1]) << 16);
    pk[1] = (u32)f2h(d[2]) | ((u32)f2h(d[3]) << 16);
    *(u32x2*)&QEi[(i0 + lr) * 132 + tb] = pk;
  }
  // KE = mfma(Ek-rows, K-rows): D[m=t'][n=j] -> lane t'=tt*16+4lg+e, j=jt*16+lr.
#pragma unroll
  for (int q = 0; q < 2; q++) {
    int tt = wv * 2 + q;
    h8v ea = *(const h8v*)(EkT + (tt * 16 + lr) * 32 + lg * 8);
#pragma unroll
    for (int jt = 0; jt < 4; jt++) {
      f4v d = mfma16(ea, kf[jt], z4);
      int tb = tt * 16 + 4 * lg;
      u32x2 pk;
      pk[0] = (u32)f2h(d[0]) | ((u32)f2h(d[1]) << 16);
      pk[1] = (u32)f2h(d[2]) | ((u32)f2h(d[3]) << 16);
      *(u32x2*)&KEj[(jt * 16 + lr) * 132 + tb] = pk;
    }
  }
  // qk SWAPPED: sc[jt] = mfma(K-rows, Q-rows): D[m=j][n=i] -> lane holds
  // S[i=i0+lr][j=jt*16+4lg+e] — one attention row per lane.
  f4v sc[4];
#pragma unroll
  for (int jt = 0; jt < 4; jt++) sc[jt] = mfma16(kf[jt], qf, z4);

  __syncthreads();   // QEi/KEj visible

  // row-local band gather + softmax (lane owns row i = i0+lr entirely)
  const int i = i0 + lr;
  float pv[4][4];    // [jt][e]
  {
    int qbase = i * 133 + 63 - 4 * lg;          // QEi: off = i*132 + (i+63-j)
    int kbase = 8448 + 4 * lg * 133 + 63 - i;   // KEj: off = j*132 + (63+j-i)
#pragma unroll
    for (int jt = 0; jt < 4; jt++)
#pragma unroll
      for (int e = 0; e < 4; e++) {
        float qr = (float)bits2h(POOL[qbase - 16 * jt - e]);
        float kr = (float)bits2h(POOL[kbase + 2128 * jt + 133 * e]);
        pv[jt][e] = sc[jt][e] + qr + kr;
      }
  }
  float inv;
  {
    float m = pv[0][0];
#pragma unroll
    for (int jt = 0; jt < 4; jt++)
#pragma unroll
      for (int e = 0; e < 4; e++) m = fmaxf(m, pv[jt][e]);
    m = fmaxf(m, __shfl_xor(m, 16));
    m = fmaxf(m, __shfl_xor(m, 32));
    float t0 = 0.f;
#pragma unroll
    for (int jt = 0; jt < 4; jt++)
#pragma unroll
      for (int e = 0; e < 4; e++) {
        pv[jt][e] = exp2f((pv[jt][e] - m) * 1.4426950408889634f);
        t0 += pv[jt][e];
      }
    t0 += __shfl_xor(t0, 16);
    t0 += __shfl_xor(t0, 32);
    inv = 1.f / t0;
  }
#pragma unroll
  for (int jt = 0; jt < 4; jt++)
#pragma unroll
    for (int e = 0; e < 4; e++) pv[jt][e] *= inv;   // pre-normalize

  __syncthreads();   // all gathers done -> safe to overlay Pl/VTl/Psh

  // write P: Pl[i][j] (b64: j-run of 4 inside one 8-chunk) + Psh[i][d] (scalar)
#pragma unroll
  for (int jt = 0; jt < 4; jt++) {
    int j0 = jt * 16 + 4 * lg;
    int jc = j0 >> 3;
    u32x2 pk;
    pk[0] = (u32)f2h(pv[jt][0]) | ((u32)f2h(pv[jt][1]) << 16);
    pk[1] = (u32)f2h(pv[jt][2]) | ((u32)f2h(pv[jt][3]) << 16);
    *(u32x2*)&Pl[i * 64 + ((jc ^ (i & 7)) << 3) + (j0 & 7)] = pk;
#pragma unroll
    for (int e = 0; e < 4; e++) {
      int d = i + 63 - (j0 + e);
      int cd = d >> 3;
      Psh[i * 128 + (((cd & 8) | ((cd & 7) ^ (i & 7))) << 3) + (d & 7)] =
          f2h(pv[jt][e]);
    }
  }
  {
    // zero out-of-band Psh cells: row zi, 64 invalid cols split [0,zi) u [zi+64,128)
    int zi = tid >> 2;
#pragma unroll
    for (int kk = 0; kk < 16; kk++) {
      int k = (tid & 3) * 16 + kk;
      int col = (k < zi) ? k : (k + 64);
      int cd = col >> 3;
      Psh[zi * 128 + (((cd & 8) | ((cd & 7) ^ (zi & 7))) << 3) + (col & 7)] = 0;
    }
    int u0 = tid, j0_ = u0 >> 3, cb0 = u0 & 7;
#pragma unroll
    for (int e = 0; e < 8; e++) {
      int c = cb0 * 8 + e;
      VTl[c * 64 + (((j0_ >> 3) ^ (c & 7)) << 3) + (j0_ & 7)] = (u16)vreg0[e];
    }
    int u1 = tid + 256, j1_ = u1 >> 3, cb1 = u1 & 7;
#pragma unroll
    for (int e = 0; e < 8; e++) {
      int c = cb1 * 8 + e;
      VTl[c * 64 + (((j1_ >> 3) ^ (c & 7)) << 3) + (j1_ & 7)] = (u16)vreg1[e];
    }
  }
  __syncthreads();   // P / VT / Psh visible

  // PV + SVE accumulate into [i 16][c 64] (P pre-normalized)
  f4v acc[4] = {z4, z4, z4, z4};
  {
#pragma unroll
    for (int kc = 0; kc < 2; kc++) {
      h8v pa = *(const h8v*)&Pl[i * 64 + (((kc * 4 + lg) ^ (i & 7)) << 3)];
#pragma unroll
      for (int ct = 0; ct < 4; ct++) {
        int cA = ct * 16 + lr;
        h8v vb = *(const h8v*)&VTl[cA * 64 + (((kc * 4 + lg) ^ (cA & 7)) << 3)];
        acc[ct] = mfma16(pa, vb, acc[ct]);
      }
    }
    // SVE: Pshift[i][d] (A) x Evp[c][d] (B), K=128
#pragma unroll
    for (int tc = 0; tc < 4; tc++) {
      int cd = tc * 4 + lg;
      int cds = (cd & 8) | ((cd & 7) ^ (i & 7));
      h8v pa = *(const h8v*)&Psh[i * 128 + cds * 8];
#pragma unroll
      for (int ct = 0; ct < 4; ct++) {
        h8v eb = *(const h8v*)(Evp + (ct * 16 + lr) * 128 + tc * 32 + lg * 8);
        acc[ct] = mfma16(pa, eb, acc[ct]);
      }
    }
  }
  // store attn rows [s*64+i][g*64+c] (already normalized)
#pragma unroll
  for (int ct = 0; ct < 4; ct++)
#pragma unroll
    for (int r = 0; r < 4; r++) {
      int io = i0 + lg * 4 + r;
      attn[(size_t)(s * 64 + io) * 512 + g * 64 + ct * 16 + lr] = f2h(acc[ct][r]);
    }
}

// ---------- K3: out = attn @ Wout^T + b. W via async LDS dbuf (R16 form) ----------
__global__ __launch_bounds__(512, 4) void k3_oproj(
    const u16* __restrict__ attn, const u16* __restrict__ Woutb,
    const float* __restrict__ ob, float* __restrict__ out)
{
  __shared__ u16 POOL3[40960];     // 80KB: WD 2x16384 u16 (64KB) + Bl 2x4096 u16 (16KB)
  u16* WD = POOL3;                 // [buf][o 512][c4 4, ^ ((o>>1)&3)]
  u16* Bl = POOL3 + 32768;         // [buf][h 64][chunk 8, ^ (h&7)] (64 c per pair)
  const int bid = blockIdx.x;
  const int b = bid >> 6, w = bid & 63;
  const int tid = threadIdx.x;
  const int l = tid & 63, wv = tid >> 6;   // 8 waves, wave owns o [wv*64, +64)
  const int lr = l & 15, lg = l >> 4;
  const int osub = wv * 64;

  auto stageW = [&](int kk, int buf) {     // [512 o][32 c], 4 gll16/thread
#pragma unroll
    for (int q = 0; q < 4; q++) {
      int slot = q * 512 + tid;
      int o = slot >> 2, c4 = slot & 3;
      gll16(Woutb + (size_t)o * 512 + kk * 32 + ((c4 ^ ((o >> 1) & 3)) << 3),
            WD + buf * 16384 + slot * 8);
    }
  };
  auto stageA = [&](int pr, int buf) {     // attn pair pr: 64 c, 1 gll16/thread
    int h_l = tid >> 3, p = tid & 7;
    gll16(attn + ((size_t)b * 4096 + (size_t)h_l * 64 + w) * 512 + pr * 64 +
              ((p ^ (h_l & 7)) << 3),
          Bl + buf * 4096 + tid * 8);
  };

  stageW(0, 0);
  stageA(0, 0);
  __syncthreads();

  f4v acc[4][4];
#pragma unroll
  for (int mt = 0; mt < 4; mt++)
#pragma unroll
    for (int jt = 0; jt < 4; jt++) acc[mt][jt] = (f4v){0.f, 0.f, 0.f, 0.f};

  for (int kk = 0; kk < 16; kk++) {        // BK=32; c = kk*32 (same order as before)
    int curW = kk & 1;
    int pr = kk >> 1, curA = pr & 1;
    if (kk < 15) stageW(kk + 1, curW ^ 1);
    if ((kk & 1) == 0 && pr < 7) stageA(pr + 1, curA ^ 1);
    h8v af[4], bf[4];
#pragma unroll
    for (int mt = 0; mt < 4; mt++) {
      int o = osub + mt * 16 + lr;
      af[mt] = *(const h8v*)&WD[curW * 16384 + o * 32 +
                                ((lg ^ ((o >> 1) & 3)) << 3)];
    }
#pragma unroll
    for (int jt = 0; jt < 4; jt++) {
      int h = jt * 16 + lr;
      bf[jt] = *(const h8v*)&Bl[curA * 4096 + h * 64 +
                                ((((kk & 1) * 4 + lg) ^ (h & 7)) << 3)];
    }
#pragma unroll
    for (int mt = 0; mt < 4; mt++)
#pragma unroll
      for (int jt = 0; jt < 4; jt++)
        acc[mt][jt] = mfma16(af[mt], bf[jt], acc[mt][jt]);
    __syncthreads();                       // drains vmcnt -> next tiles visible
  }

#pragma unroll
  for (int mt = 0; mt < 4; mt++)
#pragma unroll
    for (int jt = 0; jt < 4; jt++)
#pragma unroll
      for (int e = 0; e < 4; e++) {
        int o = osub + mt * 16 + lg * 4 + e;
        int h = jt * 16 + lr;
        out[(((size_t)b * 512 + o) * 64 + w) * 64 + h] = acc[mt][jt][e] + ob[o];
      }
}

// ---------- launch ----------
extern "C" void kernel_launch(void* const* d_in, const int* in_sizes, int n_in,
                              void* d_out, int out_size, void* d_ws, size_t ws_size,
                              hipStream_t stream)
{
  (void)in_sizes; (void)n_in; (void)out_size; (void)ws_size;
  const float* x    = (const float*)d_in[0];
  const float* w1   = (const float*)d_in[1];
  const float* b1   = (const float*)d_in[2];
  const float* wout = (const float*)d_in[3];
  const float* bo   = (const float*)d_in[4];
  const float* rel  = (const float*)d_in[5];
  float* out = (float*)d_out;

  char* ws = (char*)d_ws;                       // needs ~193.6 MiB
  u16* qkv_ws  = (u16*)ws;                      // 134,217,728 B
  u16* attn_ws = (u16*)(ws + 134217728);        //  67,108,864 B
  u16* W1b     = (u16*)(ws + 201326592);        //   1,048,576 B
  u16* Woutb   = (u16*)(ws + 202375168);        //     524,288 B
  u16* EqT     = (u16*)(ws + 202899456);        //       8,192 B
  u16* EkT     = (u16*)(ws + 202907648);        //       8,192 B
  u16* Evp     = (u16*)(ws + 202915840);        //      16,384 B

  k0_setup<<<dim3(3136), dim3(256), 0, stream>>>(w1, wout, rel, W1b, Woutb, EqT, EkT, Evp);
  k1_qkv  <<<dim3(1024), dim3(256), 0, stream>>>(x, W1b, b1, qkv_ws);
  k2_attn <<<dim3(8192), dim3(256), 0, stream>>>(qkv_ws, EqT, EkT, Evp, attn_ws);
  k3_oproj<<<dim3(1024), dim3(512), 0, stream>>>(attn_ws, Woutb, bo, out);
}